// Round 5
// baseline (1747.137 us; speedup 1.0000x reference)
//
#include <hip/hip_runtime.h>
#include <math.h>

#define N_NODES 50000
#define EDGES   1250000
#define DIM     64
#define NLAYER  3
#define BATCH   4096

#define NBUCK 196   // coarse buckets: bucket = row >> 8 (256 rows each)
#define RPB   256   // rows per bucket
#define NABLK 128   // phase-A blocks

// ---------------- Phase A1: per-block bucket histogram ----------------

__global__ __launch_bounds__(256) void bucket_hist_kernel(const int* __restrict__ rows,
                                                          int* __restrict__ bhist) {
    __shared__ int h[NBUCK];
    for (int i = threadIdx.x; i < NBUCK; i += 256) h[i] = 0;
    __syncthreads();
    int per = (EDGES + NABLK - 1) / NABLK;
    int e0 = blockIdx.x * per;
    int e1 = min(e0 + per, EDGES);
    for (int e = e0 + threadIdx.x; e < e1; e += 256)
        atomicAdd(&h[rows[e] >> 8], 1);
    __syncthreads();
    for (int i = threadIdx.x; i < NBUCK; i += 256)
        bhist[i * NABLK + blockIdx.x] = h[i];
}

// ---------------- Phase A2: exclusive scan of bhist (bucket-major) ----------------

__global__ __launch_bounds__(1024) void bucket_scan_kernel(const int* __restrict__ bhist,
                                                           int* __restrict__ boffs) {
    __shared__ int wsum[16];
    __shared__ int carry_s;
    int tid = threadIdx.x, lane = tid & 63, wid = tid >> 6;
    if (tid == 0) carry_s = 0;
    __syncthreads();
    const int TOTAL = NBUCK * NABLK;
    for (int basei = 0; basei < TOTAL; basei += 1024) {
        int i = basei + tid;
        int v = (i < TOTAL) ? bhist[i] : 0;
        int s = v;
#pragma unroll
        for (int off = 1; off < 64; off <<= 1) {
            int t = __shfl_up(s, off);
            if (lane >= off) s += t;
        }
        if (lane == 63) wsum[wid] = s;
        __syncthreads();
        if (wid == 0) {
            int xv = (lane < 16) ? wsum[lane] : 0;
#pragma unroll
            for (int off = 1; off < 16; off <<= 1) {
                int t = __shfl_up(xv, off);
                if (lane >= off) xv += t;
            }
            if (lane < 16) wsum[lane] = xv;
        }
        __syncthreads();
        int woff = wid ? wsum[wid - 1] : 0;
        int carry = carry_s;
        if (i < TOTAL) boffs[i] = carry + woff + s - v;
        __syncthreads();
        if (tid == 1023) carry_s = carry + woff + s;
        __syncthreads();
    }
}

// ---------------- Phase A3: scatter edges into bucket staging ----------------

__global__ __launch_bounds__(256) void bucket_scatter_kernel(const int* __restrict__ rows,
                                                             const int* __restrict__ cols,
                                                             const float* __restrict__ vals,
                                                             const int* __restrict__ boffs,
                                                             int2* __restrict__ staging) {
    __shared__ int cur[NBUCK];
    for (int i = threadIdx.x; i < NBUCK; i += 256)
        cur[i] = boffs[i * NABLK + blockIdx.x];
    __syncthreads();
    int per = (EDGES + NABLK - 1) / NABLK;
    int e0 = blockIdx.x * per;
    int e1 = min(e0 + per, EDGES);
    for (int e = e0 + threadIdx.x; e < e1; e += 256) {
        int r = rows[e];
        int p = atomicAdd(&cur[r >> 8], 1);
        staging[p] = make_int2(((r & 255) << 16) | cols[e], __float_as_int(vals[e]));
    }
}

// ---------------- Phase B: per-bucket row_ptr + final CSR ----------------

__global__ __launch_bounds__(256) void csr_build_kernel(const int* __restrict__ boffs,
                                                        const int2* __restrict__ staging,
                                                        int* __restrict__ row_ptr,
                                                        int2* __restrict__ csr) {
    __shared__ int rcur[RPB];
    __shared__ int wred[4];
    int b = blockIdx.x;
    int base = boffs[b * NABLK];
    int end = (b == NBUCK - 1) ? EDGES : boffs[(b + 1) * NABLK];
    int tid = threadIdx.x;
    rcur[tid] = 0;
    __syncthreads();
    for (int p = base + tid; p < end; p += 256)
        atomicAdd(&rcur[staging[p].x >> 16], 1);
    __syncthreads();
    int lane = tid & 63, wid = tid >> 6;
    int v = rcur[tid];
    int s = v;
#pragma unroll
    for (int off = 1; off < 64; off <<= 1) {
        int t = __shfl_up(s, off);
        if (lane >= off) s += t;
    }
    if (lane == 63) wred[wid] = s;
    __syncthreads();
    if (tid == 0) {
        int a = 0;
#pragma unroll
        for (int i = 0; i < 4; ++i) { int t = wred[i]; wred[i] = a; a += t; }
    }
    __syncthreads();
    int excl = wred[wid] + s - v;
    __syncthreads();
    rcur[tid] = base + excl;
    int row = b * RPB + tid;
    if (row < N_NODES) row_ptr[row] = base + excl;
    if (b == NBUCK - 1 && tid == 0) row_ptr[N_NODES] = EDGES;
    __syncthreads();
    for (int p = base + tid; p < end; p += 256) {
        int2 e = staging[p];
        int pos = atomicAdd(&rcur[e.x >> 16], 1);
        csr[pos] = make_int2(e.x & 0xFFFF, e.y);
    }
}

// ---------------- W transpose: w?T[l][j][d] = w?[l][d][j] ----------------

__global__ __launch_bounds__(256) void transpose_w_kernel(const float* __restrict__ w1,
                                                          const float* __restrict__ w2,
                                                          float* __restrict__ w1T,
                                                          float* __restrict__ w2T) {
    int i = blockIdx.x * 256 + threadIdx.x;
    if (i >= NLAYER * DIM * DIM) return;
    int l = i >> 12, r = i & 4095;
    int d = r >> 6, j = r & 63;
    w1T[l * 4096 + j * 64 + d] = w1[i];
    w2T[l * 4096 + j * 64 + d] = w2[i];
}

// ---------------- SpMM: one wave per row, 4 edge-groups x 16 lanes x float4 ----

__global__ __launch_bounds__(256) void spmm_kernel(const int* __restrict__ row_ptr,
                                                   const int2* __restrict__ csr,
                                                   const float* __restrict__ x,
                                                   float* __restrict__ agg) {
    int lane = threadIdx.x & 63;
    int g = lane >> 4;
    int sl = lane & 15;
    int row = blockIdx.x * 4 + (threadIdx.x >> 6);
    if (row >= N_NODES) return;
    int p0 = row_ptr[row], p1 = row_ptr[row + 1];
    float4 acc = make_float4(0.f, 0.f, 0.f, 0.f);
    int p = p0;
    for (; p + 16 <= p1; p += 16) {
        int2 a = csr[p + g];
        int2 b = csr[p + 4 + g];
        int2 c = csr[p + 8 + g];
        int2 d = csr[p + 12 + g];
        float4 xa = *(const float4*)(x + (size_t)a.x * DIM + sl * 4);
        float4 xb = *(const float4*)(x + (size_t)b.x * DIM + sl * 4);
        float4 xc = *(const float4*)(x + (size_t)c.x * DIM + sl * 4);
        float4 xd = *(const float4*)(x + (size_t)d.x * DIM + sl * 4);
        float va = __int_as_float(a.y), vb = __int_as_float(b.y);
        float vc = __int_as_float(c.y), vd = __int_as_float(d.y);
        acc.x += va * xa.x; acc.y += va * xa.y; acc.z += va * xa.z; acc.w += va * xa.w;
        acc.x += vb * xb.x; acc.y += vb * xb.y; acc.z += vb * xb.z; acc.w += vb * xb.w;
        acc.x += vc * xc.x; acc.y += vc * xc.y; acc.z += vc * xc.z; acc.w += vc * xc.w;
        acc.x += vd * xd.x; acc.y += vd * xd.y; acc.z += vd * xd.z; acc.w += vd * xd.w;
    }
    for (; p + 8 <= p1; p += 8) {
        int2 a = csr[p + g];
        int2 b = csr[p + 4 + g];
        float4 xa = *(const float4*)(x + (size_t)a.x * DIM + sl * 4);
        float4 xb = *(const float4*)(x + (size_t)b.x * DIM + sl * 4);
        float va = __int_as_float(a.y), vb = __int_as_float(b.y);
        acc.x += va * xa.x; acc.y += va * xa.y; acc.z += va * xa.z; acc.w += va * xa.w;
        acc.x += vb * xb.x; acc.y += vb * xb.y; acc.z += vb * xb.z; acc.w += vb * xb.w;
    }
    for (; p < p1; p += 4) {
        int pe = p + g;
        if (pe < p1) {
            int2 a = csr[pe];
            float4 xa = *(const float4*)(x + (size_t)a.x * DIM + sl * 4);
            float va = __int_as_float(a.y);
            acc.x += va * xa.x; acc.y += va * xa.y; acc.z += va * xa.z; acc.w += va * xa.w;
        }
    }
#pragma unroll
    for (int m = 16; m <= 32; m <<= 1) {
        acc.x += __shfl_xor(acc.x, m);
        acc.y += __shfl_xor(acc.y, m);
        acc.z += __shfl_xor(acc.z, m);
        acc.w += __shfl_xor(acc.w, m);
    }
    if (lane < 16) *(float4*)(agg + (size_t)row * DIM + lane * 4) = acc;
}

// ---------------- Dense layer: LDS, conflict-free, W staged once per block ----
// s1[d] = sum_j (x+agg)[n][j] * w1T[j][d];  s2[d] = sum_j x[n][j] * w2T[j][d]
// y[n][d] = leaky( s1 + b1[d] + agg[n][d]*(s2 + b2[d]) ),  agg = xs - xc (from LDS)

#define DTILE 32
#define NDTILES ((N_NODES + DTILE - 1) / DTILE)

__global__ __launch_bounds__(256) void dense_kernel(const float* __restrict__ x,
                                                    const float* __restrict__ agg,
                                                    const float* __restrict__ w1T,
                                                    const float* __restrict__ w2T,
                                                    const float* __restrict__ b1,
                                                    const float* __restrict__ b2,
                                                    float* __restrict__ y) {
    __shared__ float w1s[4096];
    __shared__ float w2s[4096];
    __shared__ float xs[DTILE * 64];
    __shared__ float xc[DTILE * 64];

    int tid = threadIdx.x;
    int lane = tid & 63, w = tid >> 6;

    // stage W once per block: linear float4 copies (conflict-free)
    for (int f = tid; f < 1024; f += 256) {
        ((float4*)w1s)[f] = ((const float4*)w1T)[f];
        ((float4*)w2s)[f] = ((const float4*)w2T)[f];
    }
    float b1v = b1[lane];
    float b2v = b2[lane];

    for (int tile = blockIdx.x; tile < NDTILES; tile += gridDim.x) {
        int n0 = tile * DTILE;
        __syncthreads();   // iter0: W staged; iter>0: prev compute done
        // stage x tiles, natural [n][j] layout, linear writes
        for (int f = tid; f < DTILE * 16; f += 256) {
            int n = f >> 4, q = f & 15;
            int node = n0 + n;
            int nc = (node < N_NODES) ? node : (N_NODES - 1);
            float4 xv = ((const float4*)(x + (size_t)nc * DIM))[q];
            float4 av = ((const float4*)(agg + (size_t)nc * DIM))[q];
            ((float4*)xc)[f] = xv;
            float4 sv = make_float4(xv.x + av.x, xv.y + av.y, xv.z + av.z, xv.w + av.w);
            ((float4*)xs)[f] = sv;
        }
        __syncthreads();

        // wave w: nodes n0 + w*8 .. +8; lane = output dim d
        float s1[8] = {};
        float s2[8] = {};
#pragma unroll
        for (int jq = 0; jq < 16; ++jq) {
            float wa0 = w1s[(jq * 4 + 0) * 64 + lane];
            float wa1 = w1s[(jq * 4 + 1) * 64 + lane];
            float wa2 = w1s[(jq * 4 + 2) * 64 + lane];
            float wa3 = w1s[(jq * 4 + 3) * 64 + lane];
            float wb0 = w2s[(jq * 4 + 0) * 64 + lane];
            float wb1 = w2s[(jq * 4 + 1) * 64 + lane];
            float wb2 = w2s[(jq * 4 + 2) * 64 + lane];
            float wb3 = w2s[(jq * 4 + 3) * 64 + lane];
#pragma unroll
            for (int n = 0; n < 8; ++n) {
                float4 s4 = ((const float4*)(xs + (w * 8 + n) * 64))[jq];  // broadcast
                float4 c4 = ((const float4*)(xc + (w * 8 + n) * 64))[jq];  // broadcast
                s1[n] += wa0 * s4.x + wa1 * s4.y + wa2 * s4.z + wa3 * s4.w;
                s2[n] += wb0 * c4.x + wb1 * c4.y + wb2 * c4.z + wb3 * c4.w;
            }
        }
#pragma unroll
        for (int n = 0; n < 8; ++n) {
            int nl = w * 8 + n;
            int node = n0 + nl;
            float xsv = xs[nl * 64 + lane];
            float xcv = xc[nl * 64 + lane];
            float av = xsv - xcv;  // agg[node][lane]
            float t = s1[n] + b1v + av * (s2[n] + b2v);
            t = (t > 0.f) ? t : 0.01f * t;
            if (node < N_NODES) y[(size_t)node * DIM + lane] = t;
        }
    }
}

// ---------------- Per-layer dot contributions ----------------

__global__ __launch_bounds__(256) void gather_dots_kernel(const float* __restrict__ x,
                                                          const int* __restrict__ user,
                                                          const int* __restrict__ pos,
                                                          const int* __restrict__ neg,
                                                          float* __restrict__ dst) {
    int lane = threadIdx.x & 63;
    int i = blockIdx.x * 4 + (threadIdx.x >> 6);
    if (i >= BATCH) return;
    int ui = user[i], pi = pos[i], ni = neg[i];
    float u = x[(size_t)ui * DIM + lane];
    float p = x[(size_t)pi * DIM + lane];
    float n = x[(size_t)ni * DIM + lane];
    float v = u * (p - n);
#pragma unroll
    for (int off = 32; off; off >>= 1) v += __shfl_xor(v, off);
    if (lane == 0) dst[i] = v;
}

// ---------------- Final loss ----------------

__global__ __launch_bounds__(1024) void loss_kernel(const float* __restrict__ dots,
                                                    float* __restrict__ out) {
    __shared__ float red[16];
    int tid = threadIdx.x;
    float acc = 0.f;
    for (int i = tid; i < BATCH; i += 1024) {
        float d = dots[i] + dots[BATCH + i] + dots[2 * BATCH + i] + dots[3 * BATCH + i];
        acc += fmaxf(-d, 0.f) + log1pf(expf(-fabsf(d)));
    }
#pragma unroll
    for (int off = 32; off; off >>= 1) acc += __shfl_xor(acc, off);
    if ((tid & 63) == 0) red[tid >> 6] = acc;
    __syncthreads();
    if (tid < 16) {
        float v = red[tid];
#pragma unroll
        for (int off = 8; off; off >>= 1) v += __shfl_xor(v, off);
        if (tid == 0) out[0] = v;
    }
}

// ---------------- Launch ----------------

extern "C" void kernel_launch(void* const* d_in, const int* in_sizes, int n_in,
                              void* d_out, int out_size, void* d_ws, size_t ws_size,
                              hipStream_t stream) {
    const float* emb  = (const float*)d_in[0];
    const float* w1_w = (const float*)d_in[1];
    const float* w1_b = (const float*)d_in[2];
    const float* w2_w = (const float*)d_in[3];
    const float* w2_b = (const float*)d_in[4];
    const float* vals = (const float*)d_in[5];
    const int* rows = (const int*)d_in[6];
    const int* cols = (const int*)d_in[7];
    const int* user = (const int*)d_in[8];
    const int* pos  = (const int*)d_in[9];
    const int* neg  = (const int*)d_in[10];
    float* out = (float*)d_out;

    char* w = (char*)d_ws;
    float* bufA = (float*)w;  w += (size_t)N_NODES * DIM * 4;   // also CSR staging
    float* bufB = (float*)w;  w += (size_t)N_NODES * DIM * 4;
    float* agg  = (float*)w;  w += (size_t)N_NODES * DIM * 4;
    int* row_ptr = (int*)w;   w += (((size_t)(N_NODES + 1) * 4) + 255) / 256 * 256;
    int2* csr    = (int2*)w;  w += (size_t)EDGES * 8;
    int* bhist   = (int*)w;   w += (size_t)NBUCK * NABLK * 4;
    int* boffs   = (int*)w;   w += (size_t)NBUCK * NABLK * 4;
    float* dots  = (float*)w; w += (size_t)4 * BATCH * 4;
    float* w1T   = (float*)w; w += (size_t)NLAYER * DIM * DIM * 4;
    float* w2T   = (float*)w; w += (size_t)NLAYER * DIM * DIM * 4;

    int2* staging = (int2*)bufA;

    bucket_hist_kernel<<<NABLK, 256, 0, stream>>>(rows, bhist);
    bucket_scan_kernel<<<1, 1024, 0, stream>>>(bhist, boffs);
    bucket_scatter_kernel<<<NABLK, 256, 0, stream>>>(rows, cols, vals, boffs, staging);
    csr_build_kernel<<<NBUCK, 256, 0, stream>>>(boffs, staging, row_ptr, csr);

    transpose_w_kernel<<<(NLAYER * DIM * DIM + 255) / 256, 256, 0, stream>>>(w1_w, w2_w, w1T, w2T);

    gather_dots_kernel<<<BATCH / 4, 256, 0, stream>>>(emb, user, pos, neg, dots);

    const float* x = emb;
    float* bufs[2] = {bufA, bufB};
    for (int l = 0; l < NLAYER; ++l) {
        float* y = bufs[l & 1];
        spmm_kernel<<<(N_NODES + 3) / 4, 256, 0, stream>>>(row_ptr, csr, x, agg);
        dense_kernel<<<512, 256, 0, stream>>>(
            x, agg,
            w1T + (size_t)l * DIM * DIM, w2T + (size_t)l * DIM * DIM,
            w1_b + (size_t)l * DIM, w2_b + (size_t)l * DIM,
            y);
        gather_dots_kernel<<<BATCH / 4, 256, 0, stream>>>(y, user, pos, neg,
                                                          dots + (size_t)(l + 1) * BATCH);
        x = y;
    }

    loss_kernel<<<1, 1024, 0, stream>>>(dots, out);
}

// Round 6
// 337.885 us; speedup vs baseline: 5.1708x; 5.1708x over previous
//
#include <hip/hip_runtime.h>
#include <math.h>

#define N_NODES 50000
#define EDGES   1250000
#define DIM     64
#define NLAYER  3
#define BATCH   4096

#define NBUCK 196   // coarse buckets: bucket = row >> 8 (256 rows each)
#define RPB   256   // rows per bucket
#define NABLK 128   // phase-A blocks

// ---------------- Phase A1: per-block bucket histogram ----------------

__global__ __launch_bounds__(256) void bucket_hist_kernel(const int* __restrict__ rows,
                                                          int* __restrict__ bhist) {
    __shared__ int h[NBUCK];
    for (int i = threadIdx.x; i < NBUCK; i += 256) h[i] = 0;
    __syncthreads();
    int per = (EDGES + NABLK - 1) / NABLK;
    int e0 = blockIdx.x * per;
    int e1 = min(e0 + per, EDGES);
    for (int e = e0 + threadIdx.x; e < e1; e += 256)
        atomicAdd(&h[rows[e] >> 8], 1);
    __syncthreads();
    for (int i = threadIdx.x; i < NBUCK; i += 256)
        bhist[i * NABLK + blockIdx.x] = h[i];
}

// ---------------- Phase A2: exclusive scan of bhist (bucket-major) ----------------

__global__ __launch_bounds__(1024) void bucket_scan_kernel(const int* __restrict__ bhist,
                                                           int* __restrict__ boffs) {
    __shared__ int wsum[16];
    __shared__ int carry_s;
    int tid = threadIdx.x, lane = tid & 63, wid = tid >> 6;
    if (tid == 0) carry_s = 0;
    __syncthreads();
    const int TOTAL = NBUCK * NABLK;
    for (int basei = 0; basei < TOTAL; basei += 1024) {
        int i = basei + tid;
        int v = (i < TOTAL) ? bhist[i] : 0;
        int s = v;
#pragma unroll
        for (int off = 1; off < 64; off <<= 1) {
            int t = __shfl_up(s, off);
            if (lane >= off) s += t;
        }
        if (lane == 63) wsum[wid] = s;
        __syncthreads();
        if (wid == 0) {
            int xv = (lane < 16) ? wsum[lane] : 0;
#pragma unroll
            for (int off = 1; off < 16; off <<= 1) {
                int t = __shfl_up(xv, off);
                if (lane >= off) xv += t;
            }
            if (lane < 16) wsum[lane] = xv;
        }
        __syncthreads();
        int woff = wid ? wsum[wid - 1] : 0;
        int carry = carry_s;
        if (i < TOTAL) boffs[i] = carry + woff + s - v;
        __syncthreads();
        if (tid == 1023) carry_s = carry + woff + s;
        __syncthreads();
    }
}

// ---------------- Phase A3: scatter edges into bucket staging ----------------

__global__ __launch_bounds__(256) void bucket_scatter_kernel(const int* __restrict__ rows,
                                                             const int* __restrict__ cols,
                                                             const float* __restrict__ vals,
                                                             const int* __restrict__ boffs,
                                                             int2* __restrict__ staging) {
    __shared__ int cur[NBUCK];
    for (int i = threadIdx.x; i < NBUCK; i += 256)
        cur[i] = boffs[i * NABLK + blockIdx.x];
    __syncthreads();
    int per = (EDGES + NABLK - 1) / NABLK;
    int e0 = blockIdx.x * per;
    int e1 = min(e0 + per, EDGES);
    for (int e = e0 + threadIdx.x; e < e1; e += 256) {
        int r = rows[e];
        int p = atomicAdd(&cur[r >> 8], 1);
        staging[p] = make_int2(((r & 255) << 16) | cols[e], __float_as_int(vals[e]));
    }
}

// ---------------- Phase B: per-bucket row_ptr + final CSR ----------------

__global__ __launch_bounds__(256) void csr_build_kernel(const int* __restrict__ boffs,
                                                        const int2* __restrict__ staging,
                                                        int* __restrict__ row_ptr,
                                                        int2* __restrict__ csr) {
    __shared__ int rcur[RPB];
    __shared__ int wred[4];
    int b = blockIdx.x;
    int base = boffs[b * NABLK];
    int end = (b == NBUCK - 1) ? EDGES : boffs[(b + 1) * NABLK];
    int tid = threadIdx.x;
    rcur[tid] = 0;
    __syncthreads();
    for (int p = base + tid; p < end; p += 256)
        atomicAdd(&rcur[staging[p].x >> 16], 1);
    __syncthreads();
    int lane = tid & 63, wid = tid >> 6;
    int v = rcur[tid];
    int s = v;
#pragma unroll
    for (int off = 1; off < 64; off <<= 1) {
        int t = __shfl_up(s, off);
        if (lane >= off) s += t;
    }
    if (lane == 63) wred[wid] = s;
    __syncthreads();
    if (tid == 0) {
        int a = 0;
#pragma unroll
        for (int i = 0; i < 4; ++i) { int t = wred[i]; wred[i] = a; a += t; }
    }
    __syncthreads();
    int excl = wred[wid] + s - v;
    __syncthreads();
    rcur[tid] = base + excl;
    int row = b * RPB + tid;
    if (row < N_NODES) row_ptr[row] = base + excl;
    if (b == NBUCK - 1 && tid == 0) row_ptr[N_NODES] = EDGES;
    __syncthreads();
    for (int p = base + tid; p < end; p += 256) {
        int2 e = staging[p];
        int pos = atomicAdd(&rcur[e.x >> 16], 1);
        csr[pos] = make_int2(e.x & 0xFFFF, e.y);
    }
}

// ---------------- W transpose: w?T[l][j][d] = w?[l][d][j] ----------------

__global__ __launch_bounds__(256) void transpose_w_kernel(const float* __restrict__ w1,
                                                          const float* __restrict__ w2,
                                                          float* __restrict__ w1T,
                                                          float* __restrict__ w2T) {
    int i = blockIdx.x * 256 + threadIdx.x;
    if (i >= NLAYER * DIM * DIM) return;
    int l = i >> 12, r = i & 4095;
    int d = r >> 6, j = r & 63;
    w1T[l * 4096 + j * 64 + d] = w1[i];
    w2T[l * 4096 + j * 64 + d] = w2[i];
}

// ---------------- SpMM: one wave per row, 4 edge-groups x 16 lanes x float4 ----

__global__ __launch_bounds__(256) void spmm_kernel(const int* __restrict__ row_ptr,
                                                   const int2* __restrict__ csr,
                                                   const float* __restrict__ x,
                                                   float* __restrict__ agg) {
    int lane = threadIdx.x & 63;
    int g = lane >> 4;
    int sl = lane & 15;
    int row = blockIdx.x * 4 + (threadIdx.x >> 6);
    if (row >= N_NODES) return;
    int p0 = row_ptr[row], p1 = row_ptr[row + 1];
    float4 acc = make_float4(0.f, 0.f, 0.f, 0.f);
    int p = p0;
    for (; p + 16 <= p1; p += 16) {
        int2 a = csr[p + g];
        int2 b = csr[p + 4 + g];
        int2 c = csr[p + 8 + g];
        int2 d = csr[p + 12 + g];
        float4 xa = *(const float4*)(x + (size_t)a.x * DIM + sl * 4);
        float4 xb = *(const float4*)(x + (size_t)b.x * DIM + sl * 4);
        float4 xc = *(const float4*)(x + (size_t)c.x * DIM + sl * 4);
        float4 xd = *(const float4*)(x + (size_t)d.x * DIM + sl * 4);
        float va = __int_as_float(a.y), vb = __int_as_float(b.y);
        float vc = __int_as_float(c.y), vd = __int_as_float(d.y);
        acc.x += va * xa.x; acc.y += va * xa.y; acc.z += va * xa.z; acc.w += va * xa.w;
        acc.x += vb * xb.x; acc.y += vb * xb.y; acc.z += vb * xb.z; acc.w += vb * xb.w;
        acc.x += vc * xc.x; acc.y += vc * xc.y; acc.z += vc * xc.z; acc.w += vc * xc.w;
        acc.x += vd * xd.x; acc.y += vd * xd.y; acc.z += vd * xd.z; acc.w += vd * xd.w;
    }
    for (; p + 8 <= p1; p += 8) {
        int2 a = csr[p + g];
        int2 b = csr[p + 4 + g];
        float4 xa = *(const float4*)(x + (size_t)a.x * DIM + sl * 4);
        float4 xb = *(const float4*)(x + (size_t)b.x * DIM + sl * 4);
        float va = __int_as_float(a.y), vb = __int_as_float(b.y);
        acc.x += va * xa.x; acc.y += va * xa.y; acc.z += va * xa.z; acc.w += va * xa.w;
        acc.x += vb * xb.x; acc.y += vb * xb.y; acc.z += vb * xb.z; acc.w += vb * xb.w;
    }
    for (; p < p1; p += 4) {
        int pe = p + g;
        if (pe < p1) {
            int2 a = csr[pe];
            float4 xa = *(const float4*)(x + (size_t)a.x * DIM + sl * 4);
            float va = __int_as_float(a.y);
            acc.x += va * xa.x; acc.y += va * xa.y; acc.z += va * xa.z; acc.w += va * xa.w;
        }
    }
#pragma unroll
    for (int m = 16; m <= 32; m <<= 1) {
        acc.x += __shfl_xor(acc.x, m);
        acc.y += __shfl_xor(acc.y, m);
        acc.z += __shfl_xor(acc.z, m);
        acc.w += __shfl_xor(acc.w, m);
    }
    if (lane < 16) *(float4*)(agg + (size_t)row * DIM + lane * 4) = acc;
}

// ---------------- Dense layer: LDS, conflict-free, bounded unroll (no spill) ----
// s1[d] = sum_j (x+agg)[n][j] * w1T[j][d];  s2[d] = sum_j x[n][j] * w2T[j][d]
// y[n][d] = leaky( s1 + b1[d] + agg[n][d]*(s2 + b2[d]) ),  agg = xs - xc (from LDS)

#define DTILE 32
#define NDTILES ((N_NODES + DTILE - 1) / DTILE)

__global__ __launch_bounds__(256) void dense_kernel(const float* __restrict__ x,
                                                    const float* __restrict__ agg,
                                                    const float* __restrict__ w1T,
                                                    const float* __restrict__ w2T,
                                                    const float* __restrict__ b1,
                                                    const float* __restrict__ b2,
                                                    float* __restrict__ y) {
    __shared__ float w1s[4096];
    __shared__ float w2s[4096];
    __shared__ float xs[DTILE * 64];
    __shared__ float xc[DTILE * 64];

    int tid = threadIdx.x;
    int lane = tid & 63, w = tid >> 6;

    // stage W once per block: linear float4 copies (conflict-free)
    for (int f = tid; f < 1024; f += 256) {
        ((float4*)w1s)[f] = ((const float4*)w1T)[f];
        ((float4*)w2s)[f] = ((const float4*)w2T)[f];
    }
    float b1v = b1[lane];
    float b2v = b2[lane];

    for (int tile = blockIdx.x; tile < NDTILES; tile += gridDim.x) {
        int n0 = tile * DTILE;
        __syncthreads();   // iter0: W staged; iter>0: prev compute done
        // stage x tiles, natural [n][j] layout, linear writes
        for (int f = tid; f < DTILE * 16; f += 256) {
            int n = f >> 4, q = f & 15;
            int node = n0 + n;
            int nc = (node < N_NODES) ? node : (N_NODES - 1);
            float4 xv = ((const float4*)(x + (size_t)nc * DIM))[q];
            float4 av = ((const float4*)(agg + (size_t)nc * DIM))[q];
            ((float4*)xc)[f] = xv;
            float4 sv = make_float4(xv.x + av.x, xv.y + av.y, xv.z + av.z, xv.w + av.w);
            ((float4*)xs)[f] = sv;
        }
        __syncthreads();

        // wave w: nodes n0 + w*8 .. +8; lane = output dim d
        float s1[8] = {};
        float s2[8] = {};
#pragma unroll 2
        for (int jq = 0; jq < 16; ++jq) {
            float4 wa = *(const float4*)(&w1s[jq * 4 * 64 + lane]) ;  // placeholder removed below
            (void)wa;
            float wa0 = w1s[(jq * 4 + 0) * 64 + lane];
            float wa1 = w1s[(jq * 4 + 1) * 64 + lane];
            float wa2 = w1s[(jq * 4 + 2) * 64 + lane];
            float wa3 = w1s[(jq * 4 + 3) * 64 + lane];
            float wb0 = w2s[(jq * 4 + 0) * 64 + lane];
            float wb1 = w2s[(jq * 4 + 1) * 64 + lane];
            float wb2 = w2s[(jq * 4 + 2) * 64 + lane];
            float wb3 = w2s[(jq * 4 + 3) * 64 + lane];
#pragma unroll
            for (int n = 0; n < 8; ++n) {
                float4 s4 = ((const float4*)(xs + (w * 8 + n) * 64))[jq];  // broadcast
                float4 c4 = ((const float4*)(xc + (w * 8 + n) * 64))[jq];  // broadcast
                s1[n] += wa0 * s4.x + wa1 * s4.y + wa2 * s4.z + wa3 * s4.w;
                s2[n] += wb0 * c4.x + wb1 * c4.y + wb2 * c4.z + wb3 * c4.w;
            }
        }
#pragma unroll
        for (int n = 0; n < 8; ++n) {
            int nl = w * 8 + n;
            int node = n0 + nl;
            float xsv = xs[nl * 64 + lane];
            float xcv = xc[nl * 64 + lane];
            float av = xsv - xcv;  // agg[node][lane]
            float t = s1[n] + b1v + av * (s2[n] + b2v);
            t = (t > 0.f) ? t : 0.01f * t;
            if (node < N_NODES) y[(size_t)node * DIM + lane] = t;
        }
    }
}

// ---------------- Per-layer dot contributions ----------------

__global__ __launch_bounds__(256) void gather_dots_kernel(const float* __restrict__ x,
                                                          const int* __restrict__ user,
                                                          const int* __restrict__ pos,
                                                          const int* __restrict__ neg,
                                                          float* __restrict__ dst) {
    int lane = threadIdx.x & 63;
    int i = blockIdx.x * 4 + (threadIdx.x >> 6);
    if (i >= BATCH) return;
    int ui = user[i], pi = pos[i], ni = neg[i];
    float u = x[(size_t)ui * DIM + lane];
    float p = x[(size_t)pi * DIM + lane];
    float n = x[(size_t)ni * DIM + lane];
    float v = u * (p - n);
#pragma unroll
    for (int off = 32; off; off >>= 1) v += __shfl_xor(v, off);
    if (lane == 0) dst[i] = v;
}

// ---------------- Final loss ----------------

__global__ __launch_bounds__(1024) void loss_kernel(const float* __restrict__ dots,
                                                    float* __restrict__ out) {
    __shared__ float red[16];
    int tid = threadIdx.x;
    float acc = 0.f;
    for (int i = tid; i < BATCH; i += 1024) {
        float d = dots[i] + dots[BATCH + i] + dots[2 * BATCH + i] + dots[3 * BATCH + i];
        acc += fmaxf(-d, 0.f) + log1pf(expf(-fabsf(d)));
    }
#pragma unroll
    for (int off = 32; off; off >>= 1) acc += __shfl_xor(acc, off);
    if ((tid & 63) == 0) red[tid >> 6] = acc;
    __syncthreads();
    if (tid < 16) {
        float v = red[tid];
#pragma unroll
        for (int off = 8; off; off >>= 1) v += __shfl_xor(v, off);
        if (tid == 0) out[0] = v;
    }
}

// ---------------- Launch ----------------

extern "C" void kernel_launch(void* const* d_in, const int* in_sizes, int n_in,
                              void* d_out, int out_size, void* d_ws, size_t ws_size,
                              hipStream_t stream) {
    const float* emb  = (const float*)d_in[0];
    const float* w1_w = (const float*)d_in[1];
    const float* w1_b = (const float*)d_in[2];
    const float* w2_w = (const float*)d_in[3];
    const float* w2_b = (const float*)d_in[4];
    const float* vals = (const float*)d_in[5];
    const int* rows = (const int*)d_in[6];
    const int* cols = (const int*)d_in[7];
    const int* user = (const int*)d_in[8];
    const int* pos  = (const int*)d_in[9];
    const int* neg  = (const int*)d_in[10];
    float* out = (float*)d_out;

    char* w = (char*)d_ws;
    float* bufA = (float*)w;  w += (size_t)N_NODES * DIM * 4;   // also CSR staging
    float* bufB = (float*)w;  w += (size_t)N_NODES * DIM * 4;
    float* agg  = (float*)w;  w += (size_t)N_NODES * DIM * 4;
    int* row_ptr = (int*)w;   w += (((size_t)(N_NODES + 1) * 4) + 255) / 256 * 256;
    int2* csr    = (int2*)w;  w += (size_t)EDGES * 8;
    int* bhist   = (int*)w;   w += (size_t)NBUCK * NABLK * 4;
    int* boffs   = (int*)w;   w += (size_t)NBUCK * NABLK * 4;
    float* dots  = (float*)w; w += (size_t)4 * BATCH * 4;
    float* w1T   = (float*)w; w += (size_t)NLAYER * DIM * DIM * 4;
    float* w2T   = (float*)w; w += (size_t)NLAYER * DIM * DIM * 4;

    int2* staging = (int2*)bufA;

    bucket_hist_kernel<<<NABLK, 256, 0, stream>>>(rows, bhist);
    bucket_scan_kernel<<<1, 1024, 0, stream>>>(bhist, boffs);
    bucket_scatter_kernel<<<NABLK, 256, 0, stream>>>(rows, cols, vals, boffs, staging);
    csr_build_kernel<<<NBUCK, 256, 0, stream>>>(boffs, staging, row_ptr, csr);

    transpose_w_kernel<<<(NLAYER * DIM * DIM + 255) / 256, 256, 0, stream>>>(w1_w, w2_w, w1T, w2T);

    gather_dots_kernel<<<BATCH / 4, 256, 0, stream>>>(emb, user, pos, neg, dots);

    const float* x = emb;
    float* bufs[2] = {bufA, bufB};
    for (int l = 0; l < NLAYER; ++l) {
        float* y = bufs[l & 1];
        spmm_kernel<<<(N_NODES + 3) / 4, 256, 0, stream>>>(row_ptr, csr, x, agg);
        dense_kernel<<<512, 256, 0, stream>>>(
            x, agg,
            w1T + (size_t)l * DIM * DIM, w2T + (size_t)l * DIM * DIM,
            w1_b + (size_t)l * DIM, w2_b + (size_t)l * DIM,
            y);
        gather_dots_kernel<<<BATCH / 4, 256, 0, stream>>>(y, user, pos, neg,
                                                          dots + (size_t)(l + 1) * BATCH);
        x = y;
    }

    loss_kernel<<<1, 1024, 0, stream>>>(dots, out);
}

// Round 7
// 281.073 us; speedup vs baseline: 6.2159x; 1.2021x over previous
//
#include <hip/hip_runtime.h>
#include <math.h>

#define N_NODES 50000
#define EDGES   1250000
#define DIM     64
#define NLAYER  3
#define BATCH   4096

#define NBUCK 196   // coarse buckets: bucket = row >> 8 (256 rows each)
#define RPB   256   // rows per bucket
#define NABLK 128   // phase-A blocks

// ---------------- Phase A1: per-block bucket histogram ----------------

__global__ __launch_bounds__(256) void bucket_hist_kernel(const int* __restrict__ rows,
                                                          int* __restrict__ bhist) {
    __shared__ int h[NBUCK];
    for (int i = threadIdx.x; i < NBUCK; i += 256) h[i] = 0;
    __syncthreads();
    int per = (EDGES + NABLK - 1) / NABLK;
    int e0 = blockIdx.x * per;
    int e1 = min(e0 + per, EDGES);
    for (int e = e0 + threadIdx.x; e < e1; e += 256)
        atomicAdd(&h[rows[e] >> 8], 1);
    __syncthreads();
    for (int i = threadIdx.x; i < NBUCK; i += 256)
        bhist[i * NABLK + blockIdx.x] = h[i];
}

// ---------------- Phase A2: exclusive scan of bhist (bucket-major) ----------------

__global__ __launch_bounds__(1024) void bucket_scan_kernel(const int* __restrict__ bhist,
                                                           int* __restrict__ boffs) {
    __shared__ int wsum[16];
    __shared__ int carry_s;
    int tid = threadIdx.x, lane = tid & 63, wid = tid >> 6;
    if (tid == 0) carry_s = 0;
    __syncthreads();
    const int TOTAL = NBUCK * NABLK;
    for (int basei = 0; basei < TOTAL; basei += 1024) {
        int i = basei + tid;
        int v = (i < TOTAL) ? bhist[i] : 0;
        int s = v;
#pragma unroll
        for (int off = 1; off < 64; off <<= 1) {
            int t = __shfl_up(s, off);
            if (lane >= off) s += t;
        }
        if (lane == 63) wsum[wid] = s;
        __syncthreads();
        if (wid == 0) {
            int xv = (lane < 16) ? wsum[lane] : 0;
#pragma unroll
            for (int off = 1; off < 16; off <<= 1) {
                int t = __shfl_up(xv, off);
                if (lane >= off) xv += t;
            }
            if (lane < 16) wsum[lane] = xv;
        }
        __syncthreads();
        int woff = wid ? wsum[wid - 1] : 0;
        int carry = carry_s;
        if (i < TOTAL) boffs[i] = carry + woff + s - v;
        __syncthreads();
        if (tid == 1023) carry_s = carry + woff + s;
        __syncthreads();
    }
}

// ---------------- Phase A3: scatter edges into bucket staging ----------------

__global__ __launch_bounds__(256) void bucket_scatter_kernel(const int* __restrict__ rows,
                                                             const int* __restrict__ cols,
                                                             const float* __restrict__ vals,
                                                             const int* __restrict__ boffs,
                                                             int2* __restrict__ staging) {
    __shared__ int cur[NBUCK];
    for (int i = threadIdx.x; i < NBUCK; i += 256)
        cur[i] = boffs[i * NABLK + blockIdx.x];
    __syncthreads();
    int per = (EDGES + NABLK - 1) / NABLK;
    int e0 = blockIdx.x * per;
    int e1 = min(e0 + per, EDGES);
    for (int e = e0 + threadIdx.x; e < e1; e += 256) {
        int r = rows[e];
        int p = atomicAdd(&cur[r >> 8], 1);
        staging[p] = make_int2(((r & 255) << 16) | cols[e], __float_as_int(vals[e]));
    }
}

// ---------------- Phase B: per-bucket row_ptr + final CSR ----------------

__global__ __launch_bounds__(256) void csr_build_kernel(const int* __restrict__ boffs,
                                                        const int2* __restrict__ staging,
                                                        int* __restrict__ row_ptr,
                                                        int2* __restrict__ csr) {
    __shared__ int rcur[RPB];
    __shared__ int wred[4];
    int b = blockIdx.x;
    int base = boffs[b * NABLK];
    int end = (b == NBUCK - 1) ? EDGES : boffs[(b + 1) * NABLK];
    int tid = threadIdx.x;
    rcur[tid] = 0;
    __syncthreads();
    for (int p = base + tid; p < end; p += 256)
        atomicAdd(&rcur[staging[p].x >> 16], 1);
    __syncthreads();
    int lane = tid & 63, wid = tid >> 6;
    int v = rcur[tid];
    int s = v;
#pragma unroll
    for (int off = 1; off < 64; off <<= 1) {
        int t = __shfl_up(s, off);
        if (lane >= off) s += t;
    }
    if (lane == 63) wred[wid] = s;
    __syncthreads();
    if (tid == 0) {
        int a = 0;
#pragma unroll
        for (int i = 0; i < 4; ++i) { int t = wred[i]; wred[i] = a; a += t; }
    }
    __syncthreads();
    int excl = wred[wid] + s - v;
    __syncthreads();
    rcur[tid] = base + excl;
    int row = b * RPB + tid;
    if (row < N_NODES) row_ptr[row] = base + excl;
    if (b == NBUCK - 1 && tid == 0) row_ptr[N_NODES] = EDGES;
    __syncthreads();
    for (int p = base + tid; p < end; p += 256) {
        int2 e = staging[p];
        int pos = atomicAdd(&rcur[e.x >> 16], 1);
        csr[pos] = make_int2(e.x & 0xFFFF, e.y);
    }
}

// ---------------- W transpose: w?T[l][j][d] = w?[l][d][j] ----------------

__global__ __launch_bounds__(256) void transpose_w_kernel(const float* __restrict__ w1,
                                                          const float* __restrict__ w2,
                                                          float* __restrict__ w1T,
                                                          float* __restrict__ w2T) {
    int i = blockIdx.x * 256 + threadIdx.x;
    if (i >= NLAYER * DIM * DIM) return;
    int l = i >> 12, r = i & 4095;
    int d = r >> 6, j = r & 63;
    w1T[l * 4096 + j * 64 + d] = w1[i];
    w2T[l * 4096 + j * 64 + d] = w2[i];
}

// ---------------- SpMM: one wave per row, 4 edge-groups x 16 lanes x float4 ----

__global__ __launch_bounds__(256) void spmm_kernel(const int* __restrict__ row_ptr,
                                                   const int2* __restrict__ csr,
                                                   const float* __restrict__ x,
                                                   float* __restrict__ agg) {
    int lane = threadIdx.x & 63;
    int g = lane >> 4;
    int sl = lane & 15;
    int row = blockIdx.x * 4 + (threadIdx.x >> 6);
    if (row >= N_NODES) return;
    int p0 = row_ptr[row], p1 = row_ptr[row + 1];
    float4 acc = make_float4(0.f, 0.f, 0.f, 0.f);
    int p = p0;
    for (; p + 16 <= p1; p += 16) {
        int2 a = csr[p + g];
        int2 b = csr[p + 4 + g];
        int2 c = csr[p + 8 + g];
        int2 d = csr[p + 12 + g];
        float4 xa = *(const float4*)(x + (size_t)a.x * DIM + sl * 4);
        float4 xb = *(const float4*)(x + (size_t)b.x * DIM + sl * 4);
        float4 xc = *(const float4*)(x + (size_t)c.x * DIM + sl * 4);
        float4 xd = *(const float4*)(x + (size_t)d.x * DIM + sl * 4);
        float va = __int_as_float(a.y), vb = __int_as_float(b.y);
        float vc = __int_as_float(c.y), vd = __int_as_float(d.y);
        acc.x += va * xa.x; acc.y += va * xa.y; acc.z += va * xa.z; acc.w += va * xa.w;
        acc.x += vb * xb.x; acc.y += vb * xb.y; acc.z += vb * xb.z; acc.w += vb * xb.w;
        acc.x += vc * xc.x; acc.y += vc * xc.y; acc.z += vc * xc.z; acc.w += vc * xc.w;
        acc.x += vd * xd.x; acc.y += vd * xd.y; acc.z += vd * xd.z; acc.w += vd * xd.w;
    }
    for (; p + 8 <= p1; p += 8) {
        int2 a = csr[p + g];
        int2 b = csr[p + 4 + g];
        float4 xa = *(const float4*)(x + (size_t)a.x * DIM + sl * 4);
        float4 xb = *(const float4*)(x + (size_t)b.x * DIM + sl * 4);
        float va = __int_as_float(a.y), vb = __int_as_float(b.y);
        acc.x += va * xa.x; acc.y += va * xa.y; acc.z += va * xa.z; acc.w += va * xa.w;
        acc.x += vb * xb.x; acc.y += vb * xb.y; acc.z += vb * xb.z; acc.w += vb * xb.w;
    }
    for (; p < p1; p += 4) {
        int pe = p + g;
        if (pe < p1) {
            int2 a = csr[pe];
            float4 xa = *(const float4*)(x + (size_t)a.x * DIM + sl * 4);
            float va = __int_as_float(a.y);
            acc.x += va * xa.x; acc.y += va * xa.y; acc.z += va * xa.z; acc.w += va * xa.w;
        }
    }
#pragma unroll
    for (int m = 16; m <= 32; m <<= 1) {
        acc.x += __shfl_xor(acc.x, m);
        acc.y += __shfl_xor(acc.y, m);
        acc.z += __shfl_xor(acc.z, m);
        acc.w += __shfl_xor(acc.w, m);
    }
    if (lane < 16) *(float4*)(agg + (size_t)row * DIM + lane * 4) = acc;
}

// ---------------- Dense layer: GEMM-style register tiling ----------------
// Block = 64 nodes x 64 dims, 4 waves (each a 32x32 quadrant), lane = 4x4 tile.
// LDS: xs/xc transposed [j][n] with XOR swizzle n^=((j&7)<<2); W natural [j][d].
// Every ds_read_b128 has 8 distinct 16B chunks (all 32 banks) -> conflict-free.

__global__ __launch_bounds__(256) void dense_kernel(const float* __restrict__ x,
                                                    const float* __restrict__ agg,
                                                    const float* __restrict__ w1T,
                                                    const float* __restrict__ w2T,
                                                    const float* __restrict__ b1,
                                                    const float* __restrict__ b2,
                                                    float* __restrict__ y) {
    __shared__ float xs[64 * 64];
    __shared__ float xc[64 * 64];
    __shared__ float w1s[64 * 64];
    __shared__ float w2s[64 * 64];

    int tid = threadIdx.x;

    // stage W: linear float4 copies, conflict-free
    for (int f = tid; f < 1024; f += 256) {
        ((float4*)w1s)[f] = ((const float4*)w1T)[f];
        ((float4*)w2s)[f] = ((const float4*)w2T)[f];
    }

    // stage x/agg: thread (n,q) handles j = q+16k; coalesced global reads,
    // swizzled writes hit all 32 banks (n low 2 bits x (q&7) high 3 bits).
    int n0 = blockIdx.x * 64;
    int q = tid & 15;
#pragma unroll
    for (int nn = 0; nn < 4; ++nn) {
        int nl = (tid >> 4) + nn * 16;
        int node = n0 + nl;
        int ncl = (node < N_NODES) ? node : (N_NODES - 1);
        const float* xrow = x + (size_t)ncl * DIM;
        const float* arow = agg + (size_t)ncl * DIM;
#pragma unroll
        for (int k = 0; k < 4; ++k) {
            int j = q + 16 * k;
            float xv = xrow[j];
            float av = arow[j];
            int idx = j * 64 + (nl ^ ((j & 7) << 2));
            xs[idx] = xv + av;
            xc[idx] = xv;
        }
    }
    __syncthreads();

    int lane = tid & 63, w = tid >> 6;
    int wn = w >> 1, wd = w & 1;
    int r = lane >> 3, c = lane & 7;
    int nb = wn * 32 + r * 4;   // node base (pre-swizzle)
    int db = wd * 32 + c * 4;   // dim base

    float s1[16] = {};
    float s2[16] = {};

#pragma unroll 2
    for (int j = 0; j < 64; ++j) {
        int swz = (j & 7) << 2;
        float4 as4 = *(const float4*)&xs[j * 64 + (nb ^ swz)];
        float4 ac4 = *(const float4*)&xc[j * 64 + (nb ^ swz)];
        float4 bw1 = *(const float4*)&w1s[j * 64 + db];
        float4 bw2 = *(const float4*)&w2s[j * 64 + db];
        float asv[4] = {as4.x, as4.y, as4.z, as4.w};
        float acv[4] = {ac4.x, ac4.y, ac4.z, ac4.w};
        float w1v[4] = {bw1.x, bw1.y, bw1.z, bw1.w};
        float w2v[4] = {bw2.x, bw2.y, bw2.z, bw2.w};
#pragma unroll
        for (int i = 0; i < 4; ++i)
#pragma unroll
            for (int k = 0; k < 4; ++k) {
                s1[i * 4 + k] += asv[i] * w1v[k];
                s2[i * 4 + k] += acv[i] * w2v[k];
            }
    }

    float4 bv1 = *(const float4*)&b1[db];
    float4 bv2 = *(const float4*)&b2[db];
    float bb1[4] = {bv1.x, bv1.y, bv1.z, bv1.w};
    float bb2[4] = {bv2.x, bv2.y, bv2.z, bv2.w};

#pragma unroll
    for (int i = 0; i < 4; ++i) {
        int nl = nb + i;
        int node = n0 + nl;
        float4 o;
        float ov[4];
#pragma unroll
        for (int k = 0; k < 4; ++k) {
            int d = db + k;
            int idx = d * 64 + (nl ^ ((d & 7) << 2));
            float ag = xs[idx] - xc[idx];     // agg[node][d]
            float t = s1[i * 4 + k] + bb1[k] + ag * (s2[i * 4 + k] + bb2[k]);
            ov[k] = (t > 0.f) ? t : 0.01f * t;
        }
        o.x = ov[0]; o.y = ov[1]; o.z = ov[2]; o.w = ov[3];
        if (node < N_NODES) *(float4*)&y[(size_t)node * DIM + db] = o;
    }
}

// ---------------- Per-layer dot contributions ----------------

__global__ __launch_bounds__(256) void gather_dots_kernel(const float* __restrict__ x,
                                                          const int* __restrict__ user,
                                                          const int* __restrict__ pos,
                                                          const int* __restrict__ neg,
                                                          float* __restrict__ dst) {
    int lane = threadIdx.x & 63;
    int i = blockIdx.x * 4 + (threadIdx.x >> 6);
    if (i >= BATCH) return;
    int ui = user[i], pi = pos[i], ni = neg[i];
    float u = x[(size_t)ui * DIM + lane];
    float p = x[(size_t)pi * DIM + lane];
    float n = x[(size_t)ni * DIM + lane];
    float v = u * (p - n);
#pragma unroll
    for (int off = 32; off; off >>= 1) v += __shfl_xor(v, off);
    if (lane == 0) dst[i] = v;
}

// ---------------- Final loss ----------------

__global__ __launch_bounds__(1024) void loss_kernel(const float* __restrict__ dots,
                                                    float* __restrict__ out) {
    __shared__ float red[16];
    int tid = threadIdx.x;
    float acc = 0.f;
    for (int i = tid; i < BATCH; i += 1024) {
        float d = dots[i] + dots[BATCH + i] + dots[2 * BATCH + i] + dots[3 * BATCH + i];
        acc += fmaxf(-d, 0.f) + log1pf(expf(-fabsf(d)));
    }
#pragma unroll
    for (int off = 32; off; off >>= 1) acc += __shfl_xor(acc, off);
    if ((tid & 63) == 0) red[tid >> 6] = acc;
    __syncthreads();
    if (tid < 16) {
        float v = red[tid];
#pragma unroll
        for (int off = 8; off; off >>= 1) v += __shfl_xor(v, off);
        if (tid == 0) out[0] = v;
    }
}

// ---------------- Launch ----------------

extern "C" void kernel_launch(void* const* d_in, const int* in_sizes, int n_in,
                              void* d_out, int out_size, void* d_ws, size_t ws_size,
                              hipStream_t stream) {
    const float* emb  = (const float*)d_in[0];
    const float* w1_w = (const float*)d_in[1];
    const float* w1_b = (const float*)d_in[2];
    const float* w2_w = (const float*)d_in[3];
    const float* w2_b = (const float*)d_in[4];
    const float* vals = (const float*)d_in[5];
    const int* rows = (const int*)d_in[6];
    const int* cols = (const int*)d_in[7];
    const int* user = (const int*)d_in[8];
    const int* pos  = (const int*)d_in[9];
    const int* neg  = (const int*)d_in[10];
    float* out = (float*)d_out;

    char* w = (char*)d_ws;
    float* bufA = (float*)w;  w += (size_t)N_NODES * DIM * 4;   // also CSR staging
    float* bufB = (float*)w;  w += (size_t)N_NODES * DIM * 4;
    float* agg  = (float*)w;  w += (size_t)N_NODES * DIM * 4;
    int* row_ptr = (int*)w;   w += (((size_t)(N_NODES + 1) * 4) + 255) / 256 * 256;
    int2* csr    = (int2*)w;  w += (size_t)EDGES * 8;
    int* bhist   = (int*)w;   w += (size_t)NBUCK * NABLK * 4;
    int* boffs   = (int*)w;   w += (size_t)NBUCK * NABLK * 4;
    float* dots  = (float*)w; w += (size_t)4 * BATCH * 4;
    float* w1T   = (float*)w; w += (size_t)NLAYER * DIM * DIM * 4;
    float* w2T   = (float*)w; w += (size_t)NLAYER * DIM * DIM * 4;

    int2* staging = (int2*)bufA;

    bucket_hist_kernel<<<NABLK, 256, 0, stream>>>(rows, bhist);
    bucket_scan_kernel<<<1, 1024, 0, stream>>>(bhist, boffs);
    bucket_scatter_kernel<<<NABLK, 256, 0, stream>>>(rows, cols, vals, boffs, staging);
    csr_build_kernel<<<NBUCK, 256, 0, stream>>>(boffs, staging, row_ptr, csr);

    transpose_w_kernel<<<(NLAYER * DIM * DIM + 255) / 256, 256, 0, stream>>>(w1_w, w2_w, w1T, w2T);

    gather_dots_kernel<<<BATCH / 4, 256, 0, stream>>>(emb, user, pos, neg, dots);

    const float* x = emb;
    float* bufs[2] = {bufA, bufB};
    for (int l = 0; l < NLAYER; ++l) {
        float* y = bufs[l & 1];
        spmm_kernel<<<(N_NODES + 3) / 4, 256, 0, stream>>>(row_ptr, csr, x, agg);
        dense_kernel<<<(N_NODES + 63) / 64, 256, 0, stream>>>(
            x, agg,
            w1T + (size_t)l * DIM * DIM, w2T + (size_t)l * DIM * DIM,
            w1_b + (size_t)l * DIM, w2_b + (size_t)l * DIM,
            y);
        gather_dots_kernel<<<BATCH / 4, 256, 0, stream>>>(y, user, pos, neg,
                                                          dots + (size_t)(l + 1) * BATCH);
        x = y;
    }

    loss_kernel<<<1, 1024, 0, stream>>>(dots, out);
}

// Round 8
// 257.626 us; speedup vs baseline: 6.7817x; 1.0910x over previous
//
#include <hip/hip_runtime.h>
#include <hip/hip_fp16.h>
#include <math.h>

#define N_NODES 50000
#define EDGES   1250000
#define DIM     64
#define NLAYER  3
#define BATCH   4096

#define NBUCK 196   // coarse buckets: bucket = row >> 8 (256 rows each)
#define RPB   256   // rows per bucket
#define NABLK 128   // phase-A blocks

static __device__ __forceinline__ ushort f2h(float f) {
    return __half_as_ushort(__float2half(f));
}
static __device__ __forceinline__ float h2f(ushort u) {
    return __half2float(__ushort_as_half(u));
}

// ---------------- Phase A1: per-block bucket histogram ----------------

__global__ __launch_bounds__(256) void bucket_hist_kernel(const int* __restrict__ rows,
                                                          int* __restrict__ bhist) {
    __shared__ int h[NBUCK];
    for (int i = threadIdx.x; i < NBUCK; i += 256) h[i] = 0;
    __syncthreads();
    int per = (EDGES + NABLK - 1) / NABLK;
    int e0 = blockIdx.x * per;
    int e1 = min(e0 + per, EDGES);
    for (int e = e0 + threadIdx.x; e < e1; e += 256)
        atomicAdd(&h[rows[e] >> 8], 1);
    __syncthreads();
    for (int i = threadIdx.x; i < NBUCK; i += 256)
        bhist[i * NABLK + blockIdx.x] = h[i];
}

// ---------------- Phase A2: exclusive scan of bhist (bucket-major) ----------------

__global__ __launch_bounds__(1024) void bucket_scan_kernel(const int* __restrict__ bhist,
                                                           int* __restrict__ boffs) {
    __shared__ int wsum[16];
    __shared__ int carry_s;
    int tid = threadIdx.x, lane = tid & 63, wid = tid >> 6;
    if (tid == 0) carry_s = 0;
    __syncthreads();
    const int TOTAL = NBUCK * NABLK;
    for (int basei = 0; basei < TOTAL; basei += 1024) {
        int i = basei + tid;
        int v = (i < TOTAL) ? bhist[i] : 0;
        int s = v;
#pragma unroll
        for (int off = 1; off < 64; off <<= 1) {
            int t = __shfl_up(s, off);
            if (lane >= off) s += t;
        }
        if (lane == 63) wsum[wid] = s;
        __syncthreads();
        if (wid == 0) {
            int xv = (lane < 16) ? wsum[lane] : 0;
#pragma unroll
            for (int off = 1; off < 16; off <<= 1) {
                int t = __shfl_up(xv, off);
                if (lane >= off) xv += t;
            }
            if (lane < 16) wsum[lane] = xv;
        }
        __syncthreads();
        int woff = wid ? wsum[wid - 1] : 0;
        int carry = carry_s;
        if (i < TOTAL) boffs[i] = carry + woff + s - v;
        __syncthreads();
        if (tid == 1023) carry_s = carry + woff + s;
        __syncthreads();
    }
}

// ---------------- Phase A3: scatter edges into bucket staging ----------------

__global__ __launch_bounds__(256) void bucket_scatter_kernel(const int* __restrict__ rows,
                                                             const int* __restrict__ cols,
                                                             const float* __restrict__ vals,
                                                             const int* __restrict__ boffs,
                                                             int2* __restrict__ staging) {
    __shared__ int cur[NBUCK];
    for (int i = threadIdx.x; i < NBUCK; i += 256)
        cur[i] = boffs[i * NABLK + blockIdx.x];
    __syncthreads();
    int per = (EDGES + NABLK - 1) / NABLK;
    int e0 = blockIdx.x * per;
    int e1 = min(e0 + per, EDGES);
    for (int e = e0 + threadIdx.x; e < e1; e += 256) {
        int r = rows[e];
        int p = atomicAdd(&cur[r >> 8], 1);
        staging[p] = make_int2(((r & 255) << 16) | cols[e], __float_as_int(vals[e]));
    }
}

// ---------------- Phase B: per-bucket row_ptr + final CSR ----------------

__global__ __launch_bounds__(256) void csr_build_kernel(const int* __restrict__ boffs,
                                                        const int2* __restrict__ staging,
                                                        int* __restrict__ row_ptr,
                                                        int2* __restrict__ csr) {
    __shared__ int rcur[RPB];
    __shared__ int wred[4];
    int b = blockIdx.x;
    int base = boffs[b * NABLK];
    int end = (b == NBUCK - 1) ? EDGES : boffs[(b + 1) * NABLK];
    int tid = threadIdx.x;
    rcur[tid] = 0;
    __syncthreads();
    for (int p = base + tid; p < end; p += 256)
        atomicAdd(&rcur[staging[p].x >> 16], 1);
    __syncthreads();
    int lane = tid & 63, wid = tid >> 6;
    int v = rcur[tid];
    int s = v;
#pragma unroll
    for (int off = 1; off < 64; off <<= 1) {
        int t = __shfl_up(s, off);
        if (lane >= off) s += t;
    }
    if (lane == 63) wred[wid] = s;
    __syncthreads();
    if (tid == 0) {
        int a = 0;
#pragma unroll
        for (int i = 0; i < 4; ++i) { int t = wred[i]; wred[i] = a; a += t; }
    }
    __syncthreads();
    int excl = wred[wid] + s - v;
    __syncthreads();
    rcur[tid] = base + excl;
    int row = b * RPB + tid;
    if (row < N_NODES) row_ptr[row] = base + excl;
    if (b == NBUCK - 1 && tid == 0) row_ptr[N_NODES] = EDGES;
    __syncthreads();
    for (int p = base + tid; p < end; p += 256) {
        int2 e = staging[p];
        int pos = atomicAdd(&rcur[e.x >> 16], 1);
        csr[pos] = make_int2(e.x & 0xFFFF, e.y);
    }
}

// ---------------- W transpose: w?T[l][j][d] = w?[l][d][j] ----------------

__global__ __launch_bounds__(256) void transpose_w_kernel(const float* __restrict__ w1,
                                                          const float* __restrict__ w2,
                                                          float* __restrict__ w1T,
                                                          float* __restrict__ w2T) {
    int i = blockIdx.x * 256 + threadIdx.x;
    if (i >= NLAYER * DIM * DIM) return;
    int l = i >> 12, r = i & 4095;
    int d = r >> 6, j = r & 63;
    w1T[l * 4096 + j * 64 + d] = w1[i];
    w2T[l * 4096 + j * 64 + d] = w2[i];
}

// ---------------- fp16 convert: xh = fp16(x) ----------------

__global__ __launch_bounds__(256) void f2h_kernel(const float* __restrict__ x,
                                                  ushort* __restrict__ xh) {
    int i = blockIdx.x * 256 + threadIdx.x;
    const int n4 = N_NODES * DIM / 4;
    if (i < n4) {
        float4 v = ((const float4*)x)[i];
        ushort4 h;
        h.x = f2h(v.x); h.y = f2h(v.y); h.z = f2h(v.z); h.w = f2h(v.w);
        ((ushort4*)xh)[i] = h;
    }
}

// ---------------- SpMM: fp16 gather (128B/row), f32 accumulate ----------------
// one wave per row, 4 edge-groups x 16 lanes x ushort4 (4 dims each)

__global__ __launch_bounds__(256) void spmm_kernel(const int* __restrict__ row_ptr,
                                                   const int2* __restrict__ csr,
                                                   const ushort* __restrict__ xh,
                                                   float* __restrict__ agg) {
    int lane = threadIdx.x & 63;
    int g = lane >> 4;
    int sl = lane & 15;
    int row = blockIdx.x * 4 + (threadIdx.x >> 6);
    if (row >= N_NODES) return;
    int p0 = row_ptr[row], p1 = row_ptr[row + 1];
    float4 acc = make_float4(0.f, 0.f, 0.f, 0.f);
    int p = p0;
    for (; p + 16 <= p1; p += 16) {
        int2 a = csr[p + g];
        int2 b = csr[p + 4 + g];
        int2 c = csr[p + 8 + g];
        int2 d = csr[p + 12 + g];
        ushort4 xa = *(const ushort4*)(xh + (size_t)a.x * DIM + sl * 4);
        ushort4 xb = *(const ushort4*)(xh + (size_t)b.x * DIM + sl * 4);
        ushort4 xc = *(const ushort4*)(xh + (size_t)c.x * DIM + sl * 4);
        ushort4 xd = *(const ushort4*)(xh + (size_t)d.x * DIM + sl * 4);
        float va = __int_as_float(a.y), vb = __int_as_float(b.y);
        float vc = __int_as_float(c.y), vd = __int_as_float(d.y);
        acc.x += va * h2f(xa.x); acc.y += va * h2f(xa.y); acc.z += va * h2f(xa.z); acc.w += va * h2f(xa.w);
        acc.x += vb * h2f(xb.x); acc.y += vb * h2f(xb.y); acc.z += vb * h2f(xb.z); acc.w += vb * h2f(xb.w);
        acc.x += vc * h2f(xc.x); acc.y += vc * h2f(xc.y); acc.z += vc * h2f(xc.z); acc.w += vc * h2f(xc.w);
        acc.x += vd * h2f(xd.x); acc.y += vd * h2f(xd.y); acc.z += vd * h2f(xd.z); acc.w += vd * h2f(xd.w);
    }
    for (; p + 8 <= p1; p += 8) {
        int2 a = csr[p + g];
        int2 b = csr[p + 4 + g];
        ushort4 xa = *(const ushort4*)(xh + (size_t)a.x * DIM + sl * 4);
        ushort4 xb = *(const ushort4*)(xh + (size_t)b.x * DIM + sl * 4);
        float va = __int_as_float(a.y), vb = __int_as_float(b.y);
        acc.x += va * h2f(xa.x); acc.y += va * h2f(xa.y); acc.z += va * h2f(xa.z); acc.w += va * h2f(xa.w);
        acc.x += vb * h2f(xb.x); acc.y += vb * h2f(xb.y); acc.z += vb * h2f(xb.z); acc.w += vb * h2f(xb.w);
    }
    for (; p < p1; p += 4) {
        int pe = p + g;
        if (pe < p1) {
            int2 a = csr[pe];
            ushort4 xa = *(const ushort4*)(xh + (size_t)a.x * DIM + sl * 4);
            float va = __int_as_float(a.y);
            acc.x += va * h2f(xa.x); acc.y += va * h2f(xa.y); acc.z += va * h2f(xa.z); acc.w += va * h2f(xa.w);
        }
    }
#pragma unroll
    for (int m = 16; m <= 32; m <<= 1) {
        acc.x += __shfl_xor(acc.x, m);
        acc.y += __shfl_xor(acc.y, m);
        acc.z += __shfl_xor(acc.z, m);
        acc.w += __shfl_xor(acc.w, m);
    }
    if (lane < 16) *(float4*)(agg + (size_t)row * DIM + lane * 4) = acc;
}

// ---------------- Dense layer: GEMM-style register tiling ----------------
// Block = 64 nodes x 64 dims, 4 waves (each a 32x32 quadrant), lane = 4x4 tile.
// Also emits fp16 mirror yh for the next layer's spmm gather.

__global__ __launch_bounds__(256) void dense_kernel(const float* __restrict__ x,
                                                    const float* __restrict__ agg,
                                                    const float* __restrict__ w1T,
                                                    const float* __restrict__ w2T,
                                                    const float* __restrict__ b1,
                                                    const float* __restrict__ b2,
                                                    float* __restrict__ y,
                                                    ushort* __restrict__ yh) {
    __shared__ float xs[64 * 64];
    __shared__ float xc[64 * 64];
    __shared__ float w1s[64 * 64];
    __shared__ float w2s[64 * 64];

    int tid = threadIdx.x;

    for (int f = tid; f < 1024; f += 256) {
        ((float4*)w1s)[f] = ((const float4*)w1T)[f];
        ((float4*)w2s)[f] = ((const float4*)w2T)[f];
    }

    int n0 = blockIdx.x * 64;
    int q = tid & 15;
#pragma unroll
    for (int nn = 0; nn < 4; ++nn) {
        int nl = (tid >> 4) + nn * 16;
        int node = n0 + nl;
        int ncl = (node < N_NODES) ? node : (N_NODES - 1);
        const float* xrow = x + (size_t)ncl * DIM;
        const float* arow = agg + (size_t)ncl * DIM;
#pragma unroll
        for (int k = 0; k < 4; ++k) {
            int j = q + 16 * k;
            float xv = xrow[j];
            float av = arow[j];
            int idx = j * 64 + (nl ^ ((j & 7) << 2));
            xs[idx] = xv + av;
            xc[idx] = xv;
        }
    }
    __syncthreads();

    int lane = tid & 63, w = tid >> 6;
    int wn = w >> 1, wd = w & 1;
    int r = lane >> 3, c = lane & 7;
    int nb = wn * 32 + r * 4;
    int db = wd * 32 + c * 4;

    float s1[16] = {};
    float s2[16] = {};

#pragma unroll 2
    for (int j = 0; j < 64; ++j) {
        int swz = (j & 7) << 2;
        float4 as4 = *(const float4*)&xs[j * 64 + (nb ^ swz)];
        float4 ac4 = *(const float4*)&xc[j * 64 + (nb ^ swz)];
        float4 bw1 = *(const float4*)&w1s[j * 64 + db];
        float4 bw2 = *(const float4*)&w2s[j * 64 + db];
        float asv[4] = {as4.x, as4.y, as4.z, as4.w};
        float acv[4] = {ac4.x, ac4.y, ac4.z, ac4.w};
        float w1v[4] = {bw1.x, bw1.y, bw1.z, bw1.w};
        float w2v[4] = {bw2.x, bw2.y, bw2.z, bw2.w};
#pragma unroll
        for (int i = 0; i < 4; ++i)
#pragma unroll
            for (int k = 0; k < 4; ++k) {
                s1[i * 4 + k] += asv[i] * w1v[k];
                s2[i * 4 + k] += acv[i] * w2v[k];
            }
    }

    float4 bv1 = *(const float4*)&b1[db];
    float4 bv2 = *(const float4*)&b2[db];
    float bb1[4] = {bv1.x, bv1.y, bv1.z, bv1.w};
    float bb2[4] = {bv2.x, bv2.y, bv2.z, bv2.w};

#pragma unroll
    for (int i = 0; i < 4; ++i) {
        int nl = nb + i;
        int node = n0 + nl;
        float4 o;
        float ov[4];
#pragma unroll
        for (int k = 0; k < 4; ++k) {
            int d = db + k;
            int idx = d * 64 + (nl ^ ((d & 7) << 2));
            float ag = xs[idx] - xc[idx];
            float t = s1[i * 4 + k] + bb1[k] + ag * (s2[i * 4 + k] + bb2[k]);
            ov[k] = (t > 0.f) ? t : 0.01f * t;
        }
        o.x = ov[0]; o.y = ov[1]; o.z = ov[2]; o.w = ov[3];
        if (node < N_NODES) {
            *(float4*)&y[(size_t)node * DIM + db] = o;
            ushort4 ho;
            ho.x = f2h(ov[0]); ho.y = f2h(ov[1]); ho.z = f2h(ov[2]); ho.w = f2h(ov[3]);
            *(ushort4*)&yh[(size_t)node * DIM + db] = ho;
        }
    }
}

// ---------------- Per-layer dot contributions ----------------

__global__ __launch_bounds__(256) void gather_dots_kernel(const float* __restrict__ x,
                                                          const int* __restrict__ user,
                                                          const int* __restrict__ pos,
                                                          const int* __restrict__ neg,
                                                          float* __restrict__ dst) {
    int lane = threadIdx.x & 63;
    int i = blockIdx.x * 4 + (threadIdx.x >> 6);
    if (i >= BATCH) return;
    int ui = user[i], pi = pos[i], ni = neg[i];
    float u = x[(size_t)ui * DIM + lane];
    float p = x[(size_t)pi * DIM + lane];
    float n = x[(size_t)ni * DIM + lane];
    float v = u * (p - n);
#pragma unroll
    for (int off = 32; off; off >>= 1) v += __shfl_xor(v, off);
    if (lane == 0) dst[i] = v;
}

// ---------------- Final loss ----------------

__global__ __launch_bounds__(1024) void loss_kernel(const float* __restrict__ dots,
                                                    float* __restrict__ out) {
    __shared__ float red[16];
    int tid = threadIdx.x;
    float acc = 0.f;
    for (int i = tid; i < BATCH; i += 1024) {
        float d = dots[i] + dots[BATCH + i] + dots[2 * BATCH + i] + dots[3 * BATCH + i];
        acc += fmaxf(-d, 0.f) + log1pf(expf(-fabsf(d)));
    }
#pragma unroll
    for (int off = 32; off; off >>= 1) acc += __shfl_xor(acc, off);
    if ((tid & 63) == 0) red[tid >> 6] = acc;
    __syncthreads();
    if (tid < 16) {
        float v = red[tid];
#pragma unroll
        for (int off = 8; off; off >>= 1) v += __shfl_xor(v, off);
        if (tid == 0) out[0] = v;
    }
}

// ---------------- Launch ----------------

extern "C" void kernel_launch(void* const* d_in, const int* in_sizes, int n_in,
                              void* d_out, int out_size, void* d_ws, size_t ws_size,
                              hipStream_t stream) {
    const float* emb  = (const float*)d_in[0];
    const float* w1_w = (const float*)d_in[1];
    const float* w1_b = (const float*)d_in[2];
    const float* w2_w = (const float*)d_in[3];
    const float* w2_b = (const float*)d_in[4];
    const float* vals = (const float*)d_in[5];
    const int* rows = (const int*)d_in[6];
    const int* cols = (const int*)d_in[7];
    const int* user = (const int*)d_in[8];
    const int* pos  = (const int*)d_in[9];
    const int* neg  = (const int*)d_in[10];
    float* out = (float*)d_out;

    char* w = (char*)d_ws;
    float* bufA = (float*)w;  w += (size_t)N_NODES * DIM * 4;   // also CSR staging
    float* bufB = (float*)w;  w += (size_t)N_NODES * DIM * 4;
    float* agg  = (float*)w;  w += (size_t)N_NODES * DIM * 4;
    int* row_ptr = (int*)w;   w += (((size_t)(N_NODES + 1) * 4) + 255) / 256 * 256;
    int2* csr    = (int2*)w;  w += (size_t)EDGES * 8;
    int* bhist   = (int*)w;   w += (size_t)NBUCK * NABLK * 4;
    int* boffs   = (int*)w;   w += (size_t)NBUCK * NABLK * 4;
    float* dots  = (float*)w; w += (size_t)4 * BATCH * 4;
    float* w1T   = (float*)w; w += (size_t)NLAYER * DIM * DIM * 4;
    float* w2T   = (float*)w; w += (size_t)NLAYER * DIM * DIM * 4;
    ushort* xh   = (ushort*)w; w += (size_t)N_NODES * DIM * 2;

    int2* staging = (int2*)bufA;

    bucket_hist_kernel<<<NABLK, 256, 0, stream>>>(rows, bhist);
    bucket_scan_kernel<<<1, 1024, 0, stream>>>(bhist, boffs);
    bucket_scatter_kernel<<<NABLK, 256, 0, stream>>>(rows, cols, vals, boffs, staging);
    csr_build_kernel<<<NBUCK, 256, 0, stream>>>(boffs, staging, row_ptr, csr);

    transpose_w_kernel<<<(NLAYER * DIM * DIM + 255) / 256, 256, 0, stream>>>(w1_w, w2_w, w1T, w2T);
    f2h_kernel<<<(N_NODES * DIM / 4 + 255) / 256, 256, 0, stream>>>(emb, xh);

    gather_dots_kernel<<<BATCH / 4, 256, 0, stream>>>(emb, user, pos, neg, dots);

    const float* x = emb;
    float* bufs[2] = {bufA, bufB};
    for (int l = 0; l < NLAYER; ++l) {
        float* y = bufs[l & 1];
        spmm_kernel<<<(N_NODES + 3) / 4, 256, 0, stream>>>(row_ptr, csr, xh, agg);
        dense_kernel<<<(N_NODES + 63) / 64, 256, 0, stream>>>(
            x, agg,
            w1T + (size_t)l * DIM * DIM, w2T + (size_t)l * DIM * DIM,
            w1_b + (size_t)l * DIM, w2_b + (size_t)l * DIM,
            y, xh);
        gather_dots_kernel<<<BATCH / 4, 256, 0, stream>>>(y, user, pos, neg,
                                                          dots + (size_t)(l + 1) * BATCH);
        x = y;
    }

    loss_kernel<<<1, 1024, 0, stream>>>(dots, out);
}